// Round 15
// baseline (681.646 us; speedup 1.0000x reference)
//
#include <hip/hip_runtime.h>

#define N_NODES 100000
#define N_EDGES 800000
#define D 128
#define SCAN_N (4 * N_NODES)        // per-relation (dst,mask) buckets
#define SCAN_TOTAL (3 * SCAN_N)     // 1,200,000
#define SCAN_CHUNK 2048             // elems per scan block (256 thr x 8)
#define SCAN_BLOCKS 586             // ceil(1.2M / 2048)
#define SCAN_PAD (SCAN_BLOCKS * SCAN_CHUNK)  // 1,200,128 (pad zeros)

typedef _Float16 f16x8 __attribute__((ext_vector_type(8)));
typedef _Float16 f16x4 __attribute__((ext_vector_type(4)));
typedef _Float16 f16x2 __attribute__((ext_vector_type(2)));
typedef float f32x4 __attribute__((ext_vector_type(4)));

#define MFMA_F16(a, b, c) __builtin_amdgcn_mfma_f32_16x16x32_f16((a), (b), (c), 0, 0, 0)

#define CONV_BLOCKS 12500   // N*D/4/256
#define COUNT_BLOCKS 9375   // 3*E/256
#define PREPW_BLOCKS 768    // 3*4*16384/256

// ---- merged prep: conv_x | bucket-count | weight fp16 (disjoint block ranges)
__global__ __launch_bounds__(256) void prep_all(
    const float* __restrict__ x, _Float16* __restrict__ h,
    const int* __restrict__ ei0, const int* __restrict__ ei1, const int* __restrict__ ei2,
    const int* __restrict__ em0, const int* __restrict__ em1, const int* __restrict__ em2,
    int* __restrict__ cnt2, const float* __restrict__ W_l, const float* __restrict__ W_r,
    const float* __restrict__ b_l, _Float16* __restrict__ whi, float* __restrict__ bsum) {
    int b = blockIdx.x;
    int tid = threadIdx.x;
    if (b < CONV_BLOCKS) {
        int idx = b * 256 + tid;
        float4 v = reinterpret_cast<const float4*>(x)[idx];
        f16x4 o = {(_Float16)v.x, (_Float16)v.y, (_Float16)v.z, (_Float16)v.w};
        reinterpret_cast<f16x4*>(h)[idx] = o;
    } else if (b < CONV_BLOCKS + COUNT_BLOCKS) {
        int e = (b - CONV_BLOCKS) * 256 + tid;  // [0, 2.4M); r uniform per block
        int r = e / N_EDGES;
        int el = e - r * N_EDGES;
        const int* ei = (r == 0) ? ei0 : (r == 1) ? ei1 : ei2;
        const int* em = (r == 0) ? em0 : (r == 1) ? em1 : em2;
        int dst = ei[N_EDGES + el];
        int m = em[el];
        atomicAdd(&cnt2[(size_t)r * SCAN_N + dst * 4 + m], 1);
    } else {
        int idx = (b - CONV_BLOCKS - COUNT_BLOCKS) * 256 + tid;
        if (idx < 3 * 4 * 16384) {
            int i = idx / (4 * 16384);
            int rem = idx % (4 * 16384);
            int slot = rem / 16384;
            int ok = rem % 16384;
            float v;
            if (slot < 3) {
                v = W_l[(size_t)(i * 3 + slot) * 16384 + ok];
            } else {
                const float* base = W_r + (size_t)i * 3 * 16384;
                v = base[ok] + base[16384 + ok] + base[2 * 16384 + ok];
            }
            whi[idx] = (_Float16)v;
        }
        if (idx < 3 * 128) {
            int i = idx / 128, o = idx % 128;
            const float* bb = b_l + (size_t)i * 3 * 128;
            bsum[idx] = bb[o] + bb[128 + o] + bb[256 + o];
        }
    }
}

// ---- per-row int8 quantization: wave per row; scales[row] = rowmax/127
__global__ __launch_bounds__(256) void quant_rows(const _Float16* __restrict__ h,
                                                  char* __restrict__ q,
                                                  float* __restrict__ scales) {
    int row = blockIdx.x * 4 + (threadIdx.x >> 6);
    int lane = threadIdx.x & 63;
    f16x2 v = *reinterpret_cast<const f16x2*>(h + (size_t)row * D + lane * 2);
    float a0 = (float)v.x, a1 = (float)v.y;
    float m = fmaxf(fabsf(a0), fabsf(a1));
#pragma unroll
    for (int off = 32; off; off >>= 1) m = fmaxf(m, __shfl_xor(m, off));
    float k = (m > 0.f) ? 127.f / m : 0.f;
    int q0 = (int)rintf(a0 * k);
    int q1 = (int)rintf(a1 * k);
    ushort pk = (ushort)((q0 & 0xFF) | ((q1 & 0xFF) << 8));
    *reinterpret_cast<ushort*>(q + (size_t)row * D + lane * 2) = pk;
    if (lane == 0) scales[row] = m * (1.f / 127.f);
}

// ---- device-wide scan, pass 1: per-block sums (block = 2048 elems)
__global__ __launch_bounds__(256) void scan_part(const int* __restrict__ cnt2,
                                                 int* __restrict__ bsums) {
    int tid = threadIdx.x;
    size_t base = (size_t)blockIdx.x * SCAN_CHUNK + tid * 8;
    int4 v0 = *reinterpret_cast<const int4*>(cnt2 + base);
    int4 v1 = *reinterpret_cast<const int4*>(cnt2 + base + 4);
    int s = v0.x + v0.y + v0.z + v0.w + v1.x + v1.y + v1.z + v1.w;
    __shared__ int red[256];
    red[tid] = s;
    __syncthreads();
    for (int off = 128; off > 0; off >>= 1) {
        if (tid < off) red[tid] += red[tid + off];
        __syncthreads();
    }
    if (tid == 0) bsums[blockIdx.x] = red[0];
}

// ---- pass 2: exclusive scan of the 586 block sums (in place), one block
__global__ __launch_bounds__(1024) void scan_tops(int* __restrict__ bsums) {
    __shared__ int s[1024];
    int tid = threadIdx.x;
    int v = (tid < SCAN_BLOCKS) ? bsums[tid] : 0;
    s[tid] = v;
    __syncthreads();
    for (int off = 1; off < 1024; off <<= 1) {
        int x = s[tid];
        int add = (tid >= off) ? s[tid - off] : 0;
        __syncthreads();
        s[tid] = x + add;
        __syncthreads();
    }
    if (tid < SCAN_BLOCKS) bsums[tid] = s[tid] - v;  // exclusive
}

// ---- pass 3: per-block exclusive scan + offset -> bnd (global positions)
__global__ __launch_bounds__(256) void scan_out(const int* __restrict__ cnt2,
                                                const int* __restrict__ bsums,
                                                int* __restrict__ bnd) {
    int tid = threadIdx.x;
    size_t base = (size_t)blockIdx.x * SCAN_CHUNK + tid * 8;
    int4 v0 = *reinterpret_cast<const int4*>(cnt2 + base);
    int4 v1 = *reinterpret_cast<const int4*>(cnt2 + base + 4);
    int l[8] = {v0.x, v0.y, v0.z, v0.w, v1.x, v1.y, v1.z, v1.w};
    int ts = l[0] + l[1] + l[2] + l[3] + l[4] + l[5] + l[6] + l[7];
    __shared__ int s[256];
    s[tid] = ts;
    __syncthreads();
    for (int off = 1; off < 256; off <<= 1) {
        int x = s[tid];
        int add = (tid >= off) ? s[tid - off] : 0;
        __syncthreads();
        s[tid] = x + add;
        __syncthreads();
    }
    int run = bsums[blockIdx.x] + s[tid] - ts;  // exclusive offset for this thread
    int o[8];
#pragma unroll
    for (int j = 0; j < 8; j++) {
        o[j] = run;
        run += l[j];
    }
    int4 o0 = {o[0], o[1], o[2], o[3]};
    int4 o1 = {o[4], o[5], o[6], o[7]};
    *reinterpret_cast<int4*>(bnd + base) = o0;
    *reinterpret_cast<int4*>(bnd + base + 4) = o1;
}

// ---- fill: packed[pos] = src*D at global scan positions, bucketed by (rel,dst,mask)
__global__ __launch_bounds__(256) void fill3(
    const int* __restrict__ ei0, const int* __restrict__ ei1, const int* __restrict__ ei2,
    const int* __restrict__ em0, const int* __restrict__ em1, const int* __restrict__ em2,
    const int* __restrict__ bnd, int* __restrict__ fill2, int* __restrict__ packed) {
    int e = blockIdx.x * 256 + threadIdx.x;  // [0, 2.4M)
    int r = e / N_EDGES;
    int el = e - r * N_EDGES;
    const int* ei = (r == 0) ? ei0 : (r == 1) ? ei1 : ei2;
    const int* em = (r == 0) ? em0 : (r == 1) ? em1 : em2;
    int dst = ei[N_EDGES + el];
    int src = ei[el];
    int m = em[el];
    int gbk = r * SCAN_N + dst * 4 + m;
    int pos = bnd[gbk] + atomicAdd(&fill2[gbk], 1);
    packed[pos] = src * D;  // premultiplied row offset (elems for h, bytes for q)
}

// dequant-accumulate 8 int8 cols with row scale s
__device__ __forceinline__ void acc8(float* a, uint2 b, float s) {
#pragma unroll
    for (int k = 0; k < 4; k++)
        a[k] = fmaf(s, (float)((int)(b.x << (24 - 8 * k)) >> 24), a[k]);
#pragma unroll
    for (int k = 0; k < 4; k++)
        a[4 + k] = fmaf(s, (float)((int)(b.y << (24 - 8 * k)) >> 24), a[4 + k]);
}

// ---- fused layer: int8 gather (128B rows) into LDS means, then fp16 MFMA GEMM
// block = 256 thr (4 waves) = 32 dst rows x 128 cols; reads h_in/q_in, writes h_out/d_out.
__global__ __launch_bounds__(256, 6) void fused_layer(
    const _Float16* __restrict__ h_in, const char* __restrict__ q_in,
    const float* __restrict__ scales, const int* __restrict__ bnd,
    const int* __restrict__ packed, const _Float16* __restrict__ Whi,
    const float* __restrict__ bias, const int* __restrict__ node_mask, int layer,
    _Float16* __restrict__ h_out, float* __restrict__ out_f32) {
    __shared__ __align__(16) _Float16 smean[3][32][136];  // pitch 272B: aligned, 2-way banks
    int tid = threadIdx.x;
    int wid = tid >> 6;
    int lane = tid & 63;
    int row0 = blockIdx.x * 32;

    // ---- block-level early-out: node_mask sorted; if first row invalid, all 32 are.
    if (node_mask[row0] > layer) {
        if (out_f32) {
            f32x4 z = {0.f, 0.f, 0.f, 0.f};
            f32x4* o = reinterpret_cast<f32x4*>(out_f32 + (size_t)row0 * D);
#pragma unroll
            for (int k = 0; k < 4; k++) o[tid + k * 256] = z;
        } else {
            f16x8 z = (f16x8)(_Float16)0;
            f16x8* o = reinterpret_cast<f16x8*>(h_out + (size_t)row0 * D);
#pragma unroll
            for (int k = 0; k < 2; k++) o[tid + k * 256] = z;
        }
        return;
    }

    int g = lane >> 4;  // task group 0..3
    int l = lane & 15;  // lane in group: owns cols l*8..l*8+7

    // ---- phase 1: 96 (rel,node) tasks; wave runs 4 concurrent groups x 6 iters.
    // Per 4-edge chunk: ONE int4 index load + 4 independent 8B q-row loads +
    // 4 scale loads (L2-resident 400KB) + dequant-fma. Demand halved vs fp16 rows.
    const char* qbase = q_in + l * 8;
#pragma unroll 1
    for (int it = 0; it < 6; it++) {
        int t = wid * 24 + it * 4 + g;
        int r = t >> 5;
        int n = t & 31;
        if (node_mask[row0 + n] > layer) continue;  // output row forced 0; skip gather
        const int* B = bnd + (size_t)r * SCAN_N + (row0 + n) * 4;
        int beg = B[0];
        int end = B[layer + 1];  // prefix: all edges with mask <= layer
        int deg = end - beg;
        float a[8] = {};
#pragma unroll 1
        for (int e4 = beg & ~3; e4 < end; e4 += 4) {
            int4 s4 = *reinterpret_cast<const int4*>(packed + e4);  // 16B-aligned, group-uniform
            if (e4 >= beg && e4 + 4 <= end) {  // interior chunk (uniform branch)
                uint2 b0 = *reinterpret_cast<const uint2*>(qbase + (size_t)(uint)s4.x);
                uint2 b1 = *reinterpret_cast<const uint2*>(qbase + (size_t)(uint)s4.y);
                uint2 b2 = *reinterpret_cast<const uint2*>(qbase + (size_t)(uint)s4.z);
                uint2 b3 = *reinterpret_cast<const uint2*>(qbase + (size_t)(uint)s4.w);
                float f0 = scales[(uint)s4.x >> 7];
                float f1 = scales[(uint)s4.y >> 7];
                float f2 = scales[(uint)s4.z >> 7];
                float f3 = scales[(uint)s4.w >> 7];
                acc8(a, b0, f0);
                acc8(a, b1, f1);
                acc8(a, b2, f2);
                acc8(a, b3, f3);
            } else {  // boundary chunk (<=2 per task)
                int ss[4] = {s4.x, s4.y, s4.z, s4.w};
#pragma unroll
                for (int j = 0; j < 4; j++) {
                    int e = e4 + j;
                    if (e >= beg && e < end) {
                        uint2 b = *reinterpret_cast<const uint2*>(qbase + (size_t)(uint)ss[j]);
                        float f = scales[(uint)ss[j] >> 7];
                        acc8(a, b, f);
                    }
                }
            }
        }
        float inv = 1.f / fmaxf((float)deg, 1.f);
        f16x8 mv;
#pragma unroll
        for (int k = 0; k < 8; k++) mv[k] = (_Float16)(a[k] * inv);
        *reinterpret_cast<f16x8*>(&smean[r][n][l * 8]) = mv;
    }
    __syncthreads();

    // ---- phase 2: GEMM. wave -> 32 cols; 2x2 16x16 frags; K=128; single fp16 W term.
    int colbase = wid * 32;
    int ln15 = lane & 15;
    int lg = lane >> 4;
    f32x4 acc[2][2] = {};

#pragma unroll
    for (int p = 0; p < 4; p++) {
        const _Float16* Whp = Whi + (size_t)p * 16384 + (size_t)colbase * D;
#pragma unroll
        for (int ks = 0; ks < 4; ks++) {
            int kof = ks * 32 + lg * 8;
            f16x8 a0f, a1f;
            if (p < 3) {
                a0f = *reinterpret_cast<const f16x8*>(&smean[p][ln15][kof]);
                a1f = *reinterpret_cast<const f16x8*>(&smean[p][16 + ln15][kof]);
            } else {
                a0f = *reinterpret_cast<const f16x8*>(h_in + (size_t)(row0 + ln15) * D + kof);
                a1f = *reinterpret_cast<const f16x8*>(h_in + (size_t)(row0 + 16 + ln15) * D + kof);
            }
            f16x8 bh0 = *reinterpret_cast<const f16x8*>(Whp + (size_t)ln15 * D + kof);
            f16x8 bh1 = *reinterpret_cast<const f16x8*>(Whp + (size_t)(16 + ln15) * D + kof);
            acc[0][0] = MFMA_F16(a0f, bh0, acc[0][0]);
            acc[0][1] = MFMA_F16(a0f, bh1, acc[0][1]);
            acc[1][0] = MFMA_F16(a1f, bh0, acc[1][0]);
            acc[1][1] = MFMA_F16(a1f, bh1, acc[1][1]);
        }
    }

    // ---- epilogue: row = row0 + r*16 + lg*4 + j, col = colbase + cc*16 + ln15.
#pragma unroll
    for (int r = 0; r < 2; r++)
#pragma unroll
        for (int j = 0; j < 4; j++) {
            int row = row0 + r * 16 + lg * 4 + j;
            bool valid = node_mask[row] <= layer;
#pragma unroll
            for (int cc = 0; cc < 2; cc++) {
                int col = colbase + cc * 16 + ln15;
                float v = acc[r][cc][j] + bias[col];
                v = valid ? fmaxf(v, 0.f) : 0.f;
                if (out_f32)
                    out_f32[(size_t)row * D + col] = v;
                else
                    h_out[(size_t)row * D + col] = (_Float16)v;
            }
        }
}

extern "C" void kernel_launch(void* const* d_in, const int* in_sizes, int n_in,
                              void* d_out, int out_size, void* d_ws, size_t ws_size,
                              hipStream_t stream) {
    const float* x = (const float*)d_in[0];
    const int* ei0 = (const int*)d_in[1];
    const int* ei1 = (const int*)d_in[2];
    const int* ei2 = (const int*)d_in[3];
    const int* node_mask = (const int*)d_in[4];
    const int* em0 = (const int*)d_in[5];
    const int* em1 = (const int*)d_in[6];
    const int* em2 = (const int*)d_in[7];
    const float* W_l = (const float*)d_in[8];
    const float* b_l = (const float*)d_in[9];
    const float* W_r = (const float*)d_in[10];

    // workspace (~103 MB)
    _Float16* hA = (_Float16*)d_ws;                            // N*D fp16
    _Float16* hB = hA + (size_t)N_NODES * D;                   // N*D fp16
    char* qA = (char*)(hB + (size_t)N_NODES * D);              // N*D int8
    char* qB = qA + (size_t)N_NODES * D;                       // N*D int8
    float* scA = (float*)(qB + (size_t)N_NODES * D);           // N f32
    float* scB = scA + N_NODES;                                // N f32
    _Float16* whi = (_Float16*)(scB + N_NODES);                // 3*4*16384 fp16
    float* bsum = (float*)(whi + 3 * 4 * 16384);               // 3*128
    int* cnt2 = (int*)(bsum + 3 * 128);                        // SCAN_PAD (padded, zeroed)
    int* fill2 = cnt2 + SCAN_PAD;                              // SCAN_TOTAL
    int* bsums = fill2 + SCAN_TOTAL;                           // 640 (>= SCAN_BLOCKS)
    int* bnd = bsums + 640;                                    // SCAN_PAD
    int* packed = bnd + SCAN_PAD;                              // 3*E (global positions)

    // zero cnt2 (incl. padding) + fill2 in one contiguous memset
    hipMemsetAsync(cnt2, 0, (size_t)(SCAN_PAD + SCAN_TOTAL) * sizeof(int), stream);

    prep_all<<<CONV_BLOCKS + COUNT_BLOCKS + PREPW_BLOCKS, 256, 0, stream>>>(
        x, hA, ei0, ei1, ei2, em0, em1, em2, cnt2, W_l, W_r, b_l, whi, bsum);
    quant_rows<<<N_NODES / 4, 256, 0, stream>>>(hA, qA, scA);
    scan_part<<<SCAN_BLOCKS, 256, 0, stream>>>(cnt2, bsums);
    scan_tops<<<1, 1024, 0, stream>>>(bsums);
    scan_out<<<SCAN_BLOCKS, 256, 0, stream>>>(cnt2, bsums, bnd);
    fill3<<<COUNT_BLOCKS, 256, 0, stream>>>(ei0, ei1, ei2, em0, em1, em2, bnd, fill2, packed);

    // layer 3: x(hA,qA) -> hB; layer 2: hB -> hA; layer 1: hA -> d_out
    fused_layer<<<N_NODES / 32, 256, 0, stream>>>(
        hA, qA, scA, bnd, packed, whi, bsum, node_mask, 3, hB, nullptr);
    quant_rows<<<N_NODES / 4, 256, 0, stream>>>(hB, qB, scB);
    fused_layer<<<N_NODES / 32, 256, 0, stream>>>(
        hB, qB, scB, bnd, packed, whi + (size_t)1 * 4 * 16384,
        bsum + 128, node_mask, 2, hA, nullptr);
    quant_rows<<<N_NODES / 4, 256, 0, stream>>>(hA, qA, scA);
    fused_layer<<<N_NODES / 32, 256, 0, stream>>>(
        hA, qA, scA, bnd, packed, whi + (size_t)2 * 4 * 16384,
        bsum + 256, node_mask, 1, nullptr, (float*)d_out);
}

// Round 16
// 632.462 us; speedup vs baseline: 1.0778x; 1.0778x over previous
//
#include <hip/hip_runtime.h>

#define N_NODES 100000
#define N_EDGES 800000
#define D 128
#define SCAN_N (4 * N_NODES)        // per-relation (dst,mask) buckets
#define SCAN_TOTAL (3 * SCAN_N)     // 1,200,000
#define SCAN_CHUNK 2048             // elems per scan block (256 thr x 8)
#define SCAN_BLOCKS 586             // ceil(1.2M / 2048)
#define SCAN_PAD (SCAN_BLOCKS * SCAN_CHUNK)  // 1,200,128 (pad zeros)

typedef _Float16 f16x8 __attribute__((ext_vector_type(8)));
typedef _Float16 f16x4 __attribute__((ext_vector_type(4)));
typedef float f32x4 __attribute__((ext_vector_type(4)));

#define MFMA_F16(a, b, c) __builtin_amdgcn_mfma_f32_16x16x32_f16((a), (b), (c), 0, 0, 0)

#define CONV_BLOCKS 12500   // N*D/4/256
#define COUNT_BLOCKS 9375   // 3*E/256
#define PREPW_BLOCKS 768    // 3*4*16384/256

// ---- merged prep: conv_x | bucket-count | weight fp16 (disjoint block ranges)
__global__ __launch_bounds__(256) void prep_all(
    const float* __restrict__ x, _Float16* __restrict__ h,
    const int* __restrict__ ei0, const int* __restrict__ ei1, const int* __restrict__ ei2,
    const int* __restrict__ em0, const int* __restrict__ em1, const int* __restrict__ em2,
    int* __restrict__ cnt2, const float* __restrict__ W_l, const float* __restrict__ W_r,
    const float* __restrict__ b_l, _Float16* __restrict__ whi, float* __restrict__ bsum) {
    int b = blockIdx.x;
    int tid = threadIdx.x;
    if (b < CONV_BLOCKS) {
        int idx = b * 256 + tid;
        float4 v = reinterpret_cast<const float4*>(x)[idx];
        f16x4 o = {(_Float16)v.x, (_Float16)v.y, (_Float16)v.z, (_Float16)v.w};
        reinterpret_cast<f16x4*>(h)[idx] = o;
    } else if (b < CONV_BLOCKS + COUNT_BLOCKS) {
        int e = (b - CONV_BLOCKS) * 256 + tid;  // [0, 2.4M); r uniform per block
        int r = e / N_EDGES;
        int el = e - r * N_EDGES;
        const int* ei = (r == 0) ? ei0 : (r == 1) ? ei1 : ei2;
        const int* em = (r == 0) ? em0 : (r == 1) ? em1 : em2;
        int dst = ei[N_EDGES + el];
        int m = em[el];
        atomicAdd(&cnt2[(size_t)r * SCAN_N + dst * 4 + m], 1);
    } else {
        int idx = (b - CONV_BLOCKS - COUNT_BLOCKS) * 256 + tid;
        if (idx < 3 * 4 * 16384) {
            int i = idx / (4 * 16384);
            int rem = idx % (4 * 16384);
            int slot = rem / 16384;
            int ok = rem % 16384;
            float v;
            if (slot < 3) {
                v = W_l[(size_t)(i * 3 + slot) * 16384 + ok];
            } else {
                const float* base = W_r + (size_t)i * 3 * 16384;
                v = base[ok] + base[16384 + ok] + base[2 * 16384 + ok];
            }
            whi[idx] = (_Float16)v;
        }
        if (idx < 3 * 128) {
            int i = idx / 128, o = idx % 128;
            const float* bb = b_l + (size_t)i * 3 * 128;
            bsum[idx] = bb[o] + bb[128 + o] + bb[256 + o];
        }
    }
}

// ---- device-wide scan, pass 1: per-block sums (block = 2048 elems)
__global__ __launch_bounds__(256) void scan_part(const int* __restrict__ cnt2,
                                                 int* __restrict__ bsums) {
    int tid = threadIdx.x;
    size_t base = (size_t)blockIdx.x * SCAN_CHUNK + tid * 8;
    int4 v0 = *reinterpret_cast<const int4*>(cnt2 + base);
    int4 v1 = *reinterpret_cast<const int4*>(cnt2 + base + 4);
    int s = v0.x + v0.y + v0.z + v0.w + v1.x + v1.y + v1.z + v1.w;
    __shared__ int red[256];
    red[tid] = s;
    __syncthreads();
    for (int off = 128; off > 0; off >>= 1) {
        if (tid < off) red[tid] += red[tid + off];
        __syncthreads();
    }
    if (tid == 0) bsums[blockIdx.x] = red[0];
}

// ---- pass 2: exclusive scan of the 586 block sums (in place), one block
__global__ __launch_bounds__(1024) void scan_tops(int* __restrict__ bsums) {
    __shared__ int s[1024];
    int tid = threadIdx.x;
    int v = (tid < SCAN_BLOCKS) ? bsums[tid] : 0;
    s[tid] = v;
    __syncthreads();
    for (int off = 1; off < 1024; off <<= 1) {
        int x = s[tid];
        int add = (tid >= off) ? s[tid - off] : 0;
        __syncthreads();
        s[tid] = x + add;
        __syncthreads();
    }
    if (tid < SCAN_BLOCKS) bsums[tid] = s[tid] - v;  // exclusive
}

// ---- pass 3: per-block exclusive scan + offset -> bnd (global positions)
__global__ __launch_bounds__(256) void scan_out(const int* __restrict__ cnt2,
                                                const int* __restrict__ bsums,
                                                int* __restrict__ bnd) {
    int tid = threadIdx.x;
    size_t base = (size_t)blockIdx.x * SCAN_CHUNK + tid * 8;
    int4 v0 = *reinterpret_cast<const int4*>(cnt2 + base);
    int4 v1 = *reinterpret_cast<const int4*>(cnt2 + base + 4);
    int l[8] = {v0.x, v0.y, v0.z, v0.w, v1.x, v1.y, v1.z, v1.w};
    int ts = l[0] + l[1] + l[2] + l[3] + l[4] + l[5] + l[6] + l[7];
    __shared__ int s[256];
    s[tid] = ts;
    __syncthreads();
    for (int off = 1; off < 256; off <<= 1) {
        int x = s[tid];
        int add = (tid >= off) ? s[tid - off] : 0;
        __syncthreads();
        s[tid] = x + add;
        __syncthreads();
    }
    int run = bsums[blockIdx.x] + s[tid] - ts;  // exclusive offset for this thread
    int o[8];
#pragma unroll
    for (int j = 0; j < 8; j++) {
        o[j] = run;
        run += l[j];
    }
    int4 o0 = {o[0], o[1], o[2], o[3]};
    int4 o1 = {o[4], o[5], o[6], o[7]};
    *reinterpret_cast<int4*>(bnd + base) = o0;
    *reinterpret_cast<int4*>(bnd + base + 4) = o1;
}

// ---- fill: packed[pos] = src*D at global scan positions, bucketed by (rel,dst,mask)
__global__ __launch_bounds__(256) void fill3(
    const int* __restrict__ ei0, const int* __restrict__ ei1, const int* __restrict__ ei2,
    const int* __restrict__ em0, const int* __restrict__ em1, const int* __restrict__ em2,
    const int* __restrict__ bnd, int* __restrict__ fill2, int* __restrict__ packed) {
    int e = blockIdx.x * 256 + threadIdx.x;  // [0, 2.4M)
    int r = e / N_EDGES;
    int el = e - r * N_EDGES;
    const int* ei = (r == 0) ? ei0 : (r == 1) ? ei1 : ei2;
    const int* em = (r == 0) ? em0 : (r == 1) ? em1 : em2;
    int dst = ei[N_EDGES + el];
    int src = ei[el];
    int m = em[el];
    int gbk = r * SCAN_N + dst * 4 + m;
    int pos = bnd[gbk] + atomicAdd(&fill2[gbk], 1);
    packed[pos] = src * D;  // premultiplied row offset (elements)
}

// ---- fused layer: validity-skipped gather (R12 loop) + MFMA GEMM (single fp16 W)
// block = 256 thr (4 waves) = 32 dst rows x 128 cols; reads h_in, writes h_out/d_out.
__global__ __launch_bounds__(256, 8) void fused_layer(
    const _Float16* __restrict__ h_in, const int* __restrict__ bnd,
    const int* __restrict__ packed, const _Float16* __restrict__ Whi,
    const float* __restrict__ bias, const int* __restrict__ node_mask, int layer,
    _Float16* __restrict__ h_out, float* __restrict__ out_f32) {
    __shared__ __align__(16) _Float16 smean[3][32][136];  // pitch 272B: aligned, 2-way banks
    int tid = threadIdx.x;
    int wid = tid >> 6;
    int lane = tid & 63;
    int row0 = blockIdx.x * 32;

    // ---- block-level early-out: node_mask sorted; if first row invalid, all 32 are.
    if (node_mask[row0] > layer) {
        if (out_f32) {
            f32x4 z = {0.f, 0.f, 0.f, 0.f};
            f32x4* o = reinterpret_cast<f32x4*>(out_f32 + (size_t)row0 * D);
#pragma unroll
            for (int k = 0; k < 4; k++) o[tid + k * 256] = z;
        } else {
            f16x8 z = (f16x8)(_Float16)0;
            f16x8* o = reinterpret_cast<f16x8*>(h_out + (size_t)row0 * D);
#pragma unroll
            for (int k = 0; k < 2; k++) o[tid + k * 256] = z;
        }
        return;
    }

    int g = lane >> 4;  // task group 0..3
    int l = lane & 15;  // lane in group: owns cols l*8..l*8+7

    // ---- phase 1: 96 (rel,node) tasks; wave runs 4 concurrent groups x 6 iters.
    // Per 4-edge chunk: ONE aligned int4 index load (group-uniform) + 4 independent
    // row loads + 4x4 v_pk_add_f16 (proven-best R12 inner loop).
    const _Float16* hbase = h_in + l * 8;
#pragma unroll 1
    for (int it = 0; it < 6; it++) {
        int t = wid * 24 + it * 4 + g;
        int r = t >> 5;
        int n = t & 31;
        if (node_mask[row0 + n] > layer) continue;  // output row forced 0; skip gather
        const int* B = bnd + (size_t)r * SCAN_N + (row0 + n) * 4;
        int beg = B[0];
        int end = B[layer + 1];  // prefix: all edges with mask <= layer
        int deg = end - beg;
        f16x8 acc = (f16x8)(_Float16)0;
#pragma unroll 1
        for (int e4 = beg & ~3; e4 < end; e4 += 4) {
            int4 s4 = *reinterpret_cast<const int4*>(packed + e4);  // 16B-aligned, uniform in group
            if (e4 >= beg && e4 + 4 <= end) {  // interior chunk: all 4 valid (uniform branch)
                f16x8 v0 = *reinterpret_cast<const f16x8*>(hbase + (size_t)(uint)s4.x);
                f16x8 v1 = *reinterpret_cast<const f16x8*>(hbase + (size_t)(uint)s4.y);
                f16x8 v2 = *reinterpret_cast<const f16x8*>(hbase + (size_t)(uint)s4.z);
                f16x8 v3 = *reinterpret_cast<const f16x8*>(hbase + (size_t)(uint)s4.w);
                acc += v0;
                acc += v1;
                acc += v2;
                acc += v3;
            } else {  // boundary chunk (<=2 per task)
                int ss[4] = {s4.x, s4.y, s4.z, s4.w};
#pragma unroll
                for (int j = 0; j < 4; j++) {
                    int e = e4 + j;
                    if (e >= beg && e < end)
                        acc += *reinterpret_cast<const f16x8*>(hbase + (size_t)(uint)ss[j]);
                }
            }
        }
        float inv = 1.f / fmaxf((float)deg, 1.f);
        f16x8 mv;
#pragma unroll
        for (int k = 0; k < 8; k++) mv[k] = (_Float16)((float)acc[k] * inv);
        *reinterpret_cast<f16x8*>(&smean[r][n][l * 8]) = mv;
    }
    __syncthreads();

    // ---- phase 2: GEMM. wave -> 32 cols; 2x2 16x16 frags; K=128; single fp16 W term.
    // Skipped tasks leave garbage in their smean rows: harmless, since MFMA C-row r
    // depends only on A-row r, and invalid rows are forced to 0 in the epilogue.
    int colbase = wid * 32;
    int ln15 = lane & 15;
    int lg = lane >> 4;
    f32x4 acc[2][2] = {};

#pragma unroll
    for (int p = 0; p < 4; p++) {
        const _Float16* Whp = Whi + (size_t)p * 16384 + (size_t)colbase * D;
#pragma unroll
        for (int ks = 0; ks < 4; ks++) {
            int kof = ks * 32 + lg * 8;
            f16x8 a0f, a1f;
            if (p < 3) {
                a0f = *reinterpret_cast<const f16x8*>(&smean[p][ln15][kof]);
                a1f = *reinterpret_cast<const f16x8*>(&smean[p][16 + ln15][kof]);
            } else {
                a0f = *reinterpret_cast<const f16x8*>(h_in + (size_t)(row0 + ln15) * D + kof);
                a1f = *reinterpret_cast<const f16x8*>(h_in + (size_t)(row0 + 16 + ln15) * D + kof);
            }
            f16x8 bh0 = *reinterpret_cast<const f16x8*>(Whp + (size_t)ln15 * D + kof);
            f16x8 bh1 = *reinterpret_cast<const f16x8*>(Whp + (size_t)(16 + ln15) * D + kof);
            acc[0][0] = MFMA_F16(a0f, bh0, acc[0][0]);
            acc[0][1] = MFMA_F16(a0f, bh1, acc[0][1]);
            acc[1][0] = MFMA_F16(a1f, bh0, acc[1][0]);
            acc[1][1] = MFMA_F16(a1f, bh1, acc[1][1]);
        }
    }

    // ---- epilogue: row = row0 + r*16 + lg*4 + j, col = colbase + cc*16 + ln15.
#pragma unroll
    for (int r = 0; r < 2; r++)
#pragma unroll
        for (int j = 0; j < 4; j++) {
            int row = row0 + r * 16 + lg * 4 + j;
            bool valid = node_mask[row] <= layer;
#pragma unroll
            for (int cc = 0; cc < 2; cc++) {
                int col = colbase + cc * 16 + ln15;
                float v = acc[r][cc][j] + bias[col];
                v = valid ? fmaxf(v, 0.f) : 0.f;
                if (out_f32)
                    out_f32[(size_t)row * D + col] = v;
                else
                    h_out[(size_t)row * D + col] = (_Float16)v;
            }
        }
}

extern "C" void kernel_launch(void* const* d_in, const int* in_sizes, int n_in,
                              void* d_out, int out_size, void* d_ws, size_t ws_size,
                              hipStream_t stream) {
    const float* x = (const float*)d_in[0];
    const int* ei0 = (const int*)d_in[1];
    const int* ei1 = (const int*)d_in[2];
    const int* ei2 = (const int*)d_in[3];
    const int* node_mask = (const int*)d_in[4];
    const int* em0 = (const int*)d_in[5];
    const int* em1 = (const int*)d_in[6];
    const int* em2 = (const int*)d_in[7];
    const float* W_l = (const float*)d_in[8];
    const float* b_l = (const float*)d_in[9];
    const float* W_r = (const float*)d_in[10];

    // workspace (~75 MB)
    _Float16* hA = (_Float16*)d_ws;                            // N*D
    _Float16* hB = hA + (size_t)N_NODES * D;                   // N*D
    _Float16* whi = hB + (size_t)N_NODES * D;                  // 3*4*16384
    float* bsum = (float*)(whi + 3 * 4 * 16384);               // 3*128
    int* cnt2 = (int*)(bsum + 3 * 128);                        // SCAN_PAD (padded, zeroed)
    int* fill2 = cnt2 + SCAN_PAD;                              // SCAN_TOTAL
    int* bsums = fill2 + SCAN_TOTAL;                           // 640 (>= SCAN_BLOCKS)
    int* bnd = bsums + 640;                                    // SCAN_PAD
    int* packed = bnd + SCAN_PAD;                              // 3*E (global positions)

    // zero cnt2 (incl. padding) + fill2 in one contiguous memset
    hipMemsetAsync(cnt2, 0, (size_t)(SCAN_PAD + SCAN_TOTAL) * sizeof(int), stream);

    prep_all<<<CONV_BLOCKS + COUNT_BLOCKS + PREPW_BLOCKS, 256, 0, stream>>>(
        x, hA, ei0, ei1, ei2, em0, em1, em2, cnt2, W_l, W_r, b_l, whi, bsum);
    scan_part<<<SCAN_BLOCKS, 256, 0, stream>>>(cnt2, bsums);
    scan_tops<<<1, 1024, 0, stream>>>(bsums);
    scan_out<<<SCAN_BLOCKS, 256, 0, stream>>>(cnt2, bsums, bnd);
    fill3<<<COUNT_BLOCKS, 256, 0, stream>>>(ei0, ei1, ei2, em0, em1, em2, bnd, fill2, packed);

    _Float16* hin = hA;
    _Float16* hout = hB;
    for (int i = 0; i < 3; i++) {
        int layer = 3 - i;
        float* of = (i == 2) ? (float*)d_out : nullptr;
        fused_layer<<<N_NODES / 32, 256, 0, stream>>>(
            hin, bnd, packed, whi + (size_t)i * 4 * 16384,
            bsum + (size_t)i * 128, node_mask, layer, hout, of);
        _Float16* tmp = hin; hin = hout; hout = tmp;
    }
}